// Round 1
// baseline (1742.785 us; speedup 1.0000x reference)
//
#include <hip/hip_runtime.h>

#define DD 128

// ---------------- CSR build ----------------

__global__ __launch_bounds__(256) void init_counts_k(int* cn, int* ce, int N, int E, int NE) {
  int g = blockIdx.x * blockDim.x + threadIdx.x;
  if (g < NE) ce[g] = (g >= E) ? 1 : 0;   // self-loop edges E..NE-1 have 1 member
  if (g < N)  cn[g] = 1;                  // every node has its self-loop
}

__global__ __launch_bounds__(256) void hist_k(const int* __restrict__ ni, const int* __restrict__ ei,
                                              int* cn, int* ce, int nnz) {
  int stride = gridDim.x * blockDim.x;
  for (int j = blockIdx.x * blockDim.x + threadIdx.x; j < nnz; j += stride) {
    atomicAdd(&cn[ni[j]], 1);
    atomicAdd(&ce[ei[j]], 1);
  }
}

__global__ __launch_bounds__(1024) void exscan_k(const int* __restrict__ cnt, int* __restrict__ offs, int n) {
  __shared__ int sums[1024];
  __shared__ int carry;
  const int tid = threadIdx.x;
  if (tid == 0) carry = 0;
  __syncthreads();
  const int PER = 8;
  const int CH = 1024 * PER;
  for (int base = 0; base < n; base += CH) {
    int i0 = base + tid * PER;
    int v[PER]; int s = 0;
    #pragma unroll
    for (int j = 0; j < PER; ++j) { int i = i0 + j; int t = (i < n) ? cnt[i] : 0; v[j] = t; s += t; }
    sums[tid] = s;
    __syncthreads();
    for (int off = 1; off < 1024; off <<= 1) {
      int t = (tid >= off) ? sums[tid - off] : 0;
      __syncthreads();
      sums[tid] += t;
      __syncthreads();
    }
    int excl = sums[tid] - s + carry;
    #pragma unroll
    for (int j = 0; j < PER; ++j) { int i = i0 + j; if (i < n) offs[i] = excl; excl += v[j]; }
    __syncthreads();
    if (tid == 0) carry += sums[1023];
    __syncthreads();
  }
  if (tid == 0) offs[n] = carry;
}

__global__ __launch_bounds__(256) void fill_self_k(int* cur_n, int* cur_e, int* listN, int* listE,
                                                   const int* __restrict__ offs_n, const int* __restrict__ offs_e,
                                                   int N, int E, int NE) {
  int g = blockIdx.x * blockDim.x + threadIdx.x;
  if (g < NE) {
    if (g < E) cur_e[g] = offs_e[g];
    else { listE[offs_e[g]] = g - E; cur_e[g] = offs_e[g] + 1; }  // self edge's member node
  }
  if (g < N) { listN[offs_n[g]] = E + g; cur_n[g] = offs_n[g] + 1; }  // node's self edge
}

__global__ __launch_bounds__(256) void fill_nnz_k(const int* __restrict__ ni, const int* __restrict__ ei,
                                                  int* cur_n, int* cur_e, int* listN, int* listE, int nnz) {
  int stride = gridDim.x * blockDim.x;
  for (int j = blockIdx.x * blockDim.x + threadIdx.x; j < nnz; j += stride) {
    int n = ni[j], e = ei[j];
    int pn = atomicAdd(&cur_n[n], 1); listN[pn] = e;
    int pe = atomicAdd(&cur_e[e], 1); listE[pe] = n;
  }
}

__global__ __launch_bounds__(256) void make_inv_k(const int* __restrict__ cn, const int* __restrict__ ce,
                                                  float* Dn_inv, float* De_inv, int N, int NE) {
  int g = blockIdx.x * blockDim.x + threadIdx.x;
  if (g < NE) { int c = ce[g]; De_inv[g] = c ? 1.0f / (float)c : 0.0f; }
  if (g < N)  { Dn_inv[g] = 1.0f / (float)cn[g]; }
}

// ---------------- gather (ownership seg-sum, no atomics) ----------------
// MODE 0: dst = scale[row] * sum            (pre-GEMM aggregation)
// MODE 1: dst = prelu(scale[row]*sum + bias[c])  (edge features)
template<int MODE>
__global__ __launch_bounds__(128) void gather_k(const float* __restrict__ src,
                                                const int* __restrict__ offs, const int* __restrict__ list,
                                                const float* __restrict__ scale, const float* __restrict__ bias,
                                                const float* __restrict__ alphap, float* __restrict__ dst) {
  const int row = blockIdx.x;
  const int c = threadIdx.x;
  const int beg = offs[row], end = offs[row + 1];
  float a0 = 0.f, a1 = 0.f, a2 = 0.f, a3 = 0.f;
  int i = beg;
  for (; i + 3 < end; i += 4) {
    int s0 = list[i], s1 = list[i + 1], s2 = list[i + 2], s3 = list[i + 3];
    a0 += src[(size_t)s0 * DD + c];
    a1 += src[(size_t)s1 * DD + c];
    a2 += src[(size_t)s2 * DD + c];
    a3 += src[(size_t)s3 * DD + c];
  }
  for (; i < end; ++i) a0 += src[(size_t)list[i] * DD + c];
  float v = scale[row] * ((a0 + a1) + (a2 + a3));
  if constexpr (MODE == 1) {
    v += bias[c];
    float al = *alphap;
    v = (v >= 0.f) ? v : al * v;
  }
  dst[(size_t)row * DD + c] = v;
}

// ---------------- GEMM (rows x 128) @ (128 x 128), fp32, W in LDS ----------------

__device__ __forceinline__ void gemm_accum(const float* __restrict__ A, const float* __restrict__ Wl,
                                           int r0, int c0, int nrows, float acc[4][4]) {
  const float* Ar[4];
  #pragma unroll
  for (int r = 0; r < 4; ++r) {
    int rr = r0 + r; if (rr >= nrows) rr = nrows - 1;
    Ar[r] = A + (size_t)rr * DD;
  }
  for (int k = 0; k < DD; k += 4) {
    float wv[4][4];
    #pragma unroll
    for (int kk = 0; kk < 4; ++kk) {
      float4 t = *(const float4*)&Wl[(k + kk) * DD + c0];
      wv[kk][0] = t.x; wv[kk][1] = t.y; wv[kk][2] = t.z; wv[kk][3] = t.w;
    }
    #pragma unroll
    for (int r = 0; r < 4; ++r) {
      float4 av = *(const float4*)(Ar[r] + k);
      float a4[4] = {av.x, av.y, av.z, av.w};
      #pragma unroll
      for (int kk = 0; kk < 4; ++kk)
        #pragma unroll
        for (int c = 0; c < 4; ++c)
          acc[r][c] = fmaf(a4[kk], wv[kk][c], acc[r][c]);
    }
  }
}

__device__ __forceinline__ void load_W_lds(const float* __restrict__ W, float* Wl) {
  const float4* ws = (const float4*)W;
  float4* wd = (float4*)Wl;
  #pragma unroll
  for (int i = 0; i < 16; ++i) wd[threadIdx.x + i * 256] = ws[threadIdx.x + i * 256];
}

// MODE 0: out = A@W    MODE 1: out = prelu(A@W + bias)
template<int MODE>
__global__ __launch_bounds__(256) void gemm128_k(const float* __restrict__ A, const float* __restrict__ W,
                                                 const float* __restrict__ bias, const float* __restrict__ alphap,
                                                 float* __restrict__ out, int nrows) {
  __shared__ float Wl[DD * DD];
  load_W_lds(W, Wl);
  __syncthreads();
  const int cg = threadIdx.x & 31;
  const int rg = threadIdx.x >> 5;
  const int c0 = cg * 4;
  const int r0 = blockIdx.x * 32 + rg * 4;
  float acc[4][4];
  #pragma unroll
  for (int r = 0; r < 4; ++r) { acc[r][0] = 0.f; acc[r][1] = 0.f; acc[r][2] = 0.f; acc[r][3] = 0.f; }
  gemm_accum(A, Wl, r0, c0, nrows, acc);
  float al = 0.f; float b4[4] = {0.f, 0.f, 0.f, 0.f};
  if constexpr (MODE == 1) {
    al = *alphap;
    float4 bt = *(const float4*)&bias[c0];
    b4[0] = bt.x; b4[1] = bt.y; b4[2] = bt.z; b4[3] = bt.w;
  }
  #pragma unroll
  for (int r = 0; r < 4; ++r) {
    int rr = r0 + r;
    if (rr < nrows) {
      float o[4];
      #pragma unroll
      for (int c = 0; c < 4; ++c) {
        float v = acc[r][c];
        if constexpr (MODE == 1) { v += b4[c]; v = (v >= 0.f) ? v : al * v; }
        o[c] = v;
      }
      float4 st = {o[0], o[1], o[2], o[3]};
      *(float4*)&out[(size_t)rr * DD + c0] = st;
    }
  }
}

// out = prelu(A1@W1 + A2@W2 + bias)   (decoder layer, fused)
__global__ __launch_bounds__(256) void gemm128_dual_k(const float* __restrict__ A1, const float* __restrict__ W1,
                                                      const float* __restrict__ A2, const float* __restrict__ W2,
                                                      const float* __restrict__ bias, const float* __restrict__ alphap,
                                                      float* __restrict__ out, int nrows) {
  __shared__ float Wl[DD * DD];
  const int cg = threadIdx.x & 31;
  const int rg = threadIdx.x >> 5;
  const int c0 = cg * 4;
  const int r0 = blockIdx.x * 32 + rg * 4;
  float acc[4][4];
  #pragma unroll
  for (int r = 0; r < 4; ++r) { acc[r][0] = 0.f; acc[r][1] = 0.f; acc[r][2] = 0.f; acc[r][3] = 0.f; }
  load_W_lds(W1, Wl);
  __syncthreads();
  gemm_accum(A1, Wl, r0, c0, nrows, acc);
  __syncthreads();
  load_W_lds(W2, Wl);
  __syncthreads();
  gemm_accum(A2, Wl, r0, c0, nrows, acc);
  float al = *alphap;
  float4 bt = *(const float4*)&bias[c0];
  float b4[4] = {bt.x, bt.y, bt.z, bt.w};
  #pragma unroll
  for (int r = 0; r < 4; ++r) {
    int rr = r0 + r;
    if (rr < nrows) {
      float o[4];
      #pragma unroll
      for (int c = 0; c < 4; ++c) {
        float v = acc[r][c] + b4[c];
        v = (v >= 0.f) ? v : al * v;
        o[c] = v;
      }
      float4 st = {o[0], o[1], o[2], o[3]};
      *(float4*)&out[(size_t)rr * DD + c0] = st;
    }
  }
}

// ---------------- copies ----------------

__global__ __launch_bounds__(256) void copy4_k(const float4* __restrict__ src, float4* __restrict__ dst, int n4) {
  int stride = gridDim.x * blockDim.x;
  for (int i = blockIdx.x * blockDim.x + threadIdx.x; i < n4; i += stride) dst[i] = src[i];
}

__global__ __launch_bounds__(256) void concat_k(const float4* __restrict__ n1, const float4* __restrict__ n2,
                                                float4* __restrict__ nn1, int N) {
  int stride = gridDim.x * blockDim.x;
  int tot = N * 32;
  for (int g = blockIdx.x * blockDim.x + threadIdx.x; g < tot; g += stride) {
    int r = g >> 5, q = g & 31;
    nn1[(size_t)r * 64 + q] = n1[g];
    nn1[(size_t)r * 64 + 32 + q] = n2[g];
  }
}

// ---------------- host ----------------

extern "C" void kernel_launch(void* const* d_in, const int* in_sizes, int n_in,
                              void* d_out, int out_size, void* d_ws, size_t ws_size,
                              hipStream_t stream) {
  const float* x        = (const float*)d_in[0];
  const float* xx       = (const float*)d_in[1];
  const int*   node_idx = (const int*)d_in[2];
  const int*   edge_idx = (const int*)d_in[3];
  const float* alphap   = (const float*)d_in[6];
  const float* e1_Wn2e  = (const float*)d_in[7];
  const float* e1_bn2e  = (const float*)d_in[8];
  const float* e1_We2n  = (const float*)d_in[9];
  const float* e1_be2n  = (const float*)d_in[10];
  const float* e2_Wn2e  = (const float*)d_in[11];
  const float* e2_bn2e  = (const float*)d_in[12];
  const float* e2_We2n  = (const float*)d_in[13];
  const float* e2_be2n  = (const float*)d_in[14];
  const float* d1_We    = (const float*)d_in[15];
  const float* d1_Wx    = (const float*)d_in[16];
  const float* d1_b     = (const float*)d_in[17];
  const float* d2_We    = (const float*)d_in[18];
  const float* d2_Wx    = (const float*)d_in[19];
  const float* d2_b     = (const float*)d_in[20];

  const int N   = in_sizes[0] / DD;
  const int NNZ = in_sizes[2];
  const int E   = (out_size - 1024 * N) / 256;
  const int NE  = E + N;
  const long long M = (long long)NNZ + N;

  // ---- workspace carve (~45 MB) ----
  char* w = (char*)d_ws;
  auto carve = [&](size_t bytes) -> void* {
    void* p = (void*)w;
    w += (bytes + 255) & ~(size_t)255;
    return p;
  };
  int* cn      = (int*)carve((size_t)N * 4);
  int* ce      = (int*)carve((size_t)NE * 4);
  int* offs_n  = (int*)carve((size_t)(N + 1) * 4);
  int* offs_e  = (int*)carve((size_t)(NE + 1) * 4);
  int* cur_n   = (int*)carve((size_t)N * 4);
  int* cur_e   = (int*)carve((size_t)NE * 4);
  int* listN   = (int*)carve((size_t)M * 4);
  int* listE   = (int*)carve((size_t)M * 4);
  float* Dn_inv = (float*)carve((size_t)N * 4);
  float* De_inv = (float*)carve((size_t)NE * 4);
  float* e_full = (float*)carve((size_t)NE * DD * 4);

  // ---- d_out slot map (+ scratch aliasing) ----
  float* out  = (float*)d_out;
  float* scrA = out;                       // nn1 region, first N*128  (finalized last)
  float* scrB = out + (size_t)N * DD;      // nn1 region, second N*128
  float* n1   = out + (size_t)N * 256;
  float* e1o  = n1 + (size_t)N * DD;
  float* n2   = e1o + (size_t)E * DD;
  float* e2o  = n2 + (size_t)N * DD;
  float* x11  = e2o + (size_t)E * DD;
  float* x21  = x11 + (size_t)N * DD;
  float* x12  = x21 + (size_t)N * DD;
  float* x22  = x12 + (size_t)N * DD;
  float* agg1 = x22;  // agg_e1 lives in x22 slot; decoder order makes this safe
  float* agg2 = x21;  // agg_e2 lives in x21 slot

  const int thr = 256;
  const int gNE = (NE + thr - 1) / thr;
  int gNNZ = (NNZ + thr - 1) / thr; if (gNNZ > 2048) gNNZ = 2048;
  const int gGemm = (N + 31) / 32;

  // ---- CSR build + degrees ----
  init_counts_k<<<gNE, thr, 0, stream>>>(cn, ce, N, E, NE);
  hist_k<<<gNNZ, thr, 0, stream>>>(node_idx, edge_idx, cn, ce, NNZ);
  exscan_k<<<1, 1024, 0, stream>>>(cn, offs_n, N);
  exscan_k<<<1, 1024, 0, stream>>>(ce, offs_e, NE);
  fill_self_k<<<gNE, thr, 0, stream>>>(cur_n, cur_e, listN, listE, offs_n, offs_e, N, E, NE);
  fill_nnz_k<<<gNNZ, thr, 0, stream>>>(node_idx, edge_idx, cur_n, cur_e, listN, listE, NNZ);
  make_inv_k<<<gNE, thr, 0, stream>>>(cn, ce, Dn_inv, De_inv, N, NE);

  // ---- encoder ----
  auto encoder = [&](const float* X0, const float* Wn2e, const float* bn2e,
                     const float* We2n, const float* be2n,
                     float* nOut, float* aggOut, float* eOut) {
    // layer 0
    gemm128_k<0><<<gGemm, 256, 0, stream>>>(X0, Wn2e, nullptr, nullptr, scrA, N);
    gather_k<1><<<NE, DD, 0, stream>>>(scrA, offs_e, listE, De_inv, bn2e, alphap, e_full);
    gather_k<0><<<N, DD, 0, stream>>>(e_full, offs_n, listN, Dn_inv, nullptr, nullptr, scrA);
    gemm128_k<1><<<gGemm, 256, 0, stream>>>(scrA, We2n, be2n, alphap, scrB, N);
    // layer 1
    gemm128_k<0><<<gGemm, 256, 0, stream>>>(scrB, Wn2e + DD * DD, nullptr, nullptr, scrA, N);
    gather_k<1><<<NE, DD, 0, stream>>>(scrA, offs_e, listE, De_inv, bn2e + DD, alphap, e_full);
    gather_k<0><<<N, DD, 0, stream>>>(e_full, offs_n, listN, Dn_inv, nullptr, nullptr, aggOut);
    gemm128_k<1><<<gGemm, 256, 0, stream>>>(aggOut, We2n + DD * DD, be2n + DD, alphap, nOut, N);
    // e output (first E rows)
    int n4 = E * 32;
    int g = (n4 + 255) / 256; if (g > 2048) g = 2048;
    copy4_k<<<g, 256, 0, stream>>>((const float4*)e_full, (float4*)eOut, n4);
  };

  encoder(x,  e1_Wn2e, e1_bn2e, e1_We2n, e1_be2n, n1, agg1, e1o);
  encoder(xx, e2_Wn2e, e2_bn2e, e2_We2n, e2_be2n, n2, agg2, e2o);

  // ---- decoders (order matters: agg1 dies when x22 finalized, agg2 when x21 finalized) ----
  auto decoder = [&](const float* x0, const float* agg, const float* We, const float* Wx,
                     const float* b, float* outSlot) {
    gemm128_dual_k<<<gGemm, 256, 0, stream>>>(x0, Wx, agg, We, b, alphap, scrB, N);
    gemm128_dual_k<<<gGemm, 256, 0, stream>>>(scrB, Wx + DD * DD, agg, We + DD * DD, b + DD, alphap, scrA, N);
    int n4 = N * 32;
    int g = (n4 + 255) / 256; if (g > 2048) g = 2048;
    copy4_k<<<g, 256, 0, stream>>>((const float4*)scrA, (float4*)outSlot, n4);
  };

  decoder(n1, agg1, d1_We, d1_Wx, d1_b, x11);
  decoder(n1, agg1, d2_We, d2_Wx, d2_b, x22);  // destroys agg1 at the end (last use)
  decoder(n2, agg2, d1_We, d1_Wx, d1_b, x12);
  decoder(n2, agg2, d2_We, d2_Wx, d2_b, x21);  // destroys agg2 at the end (last use)

  // ---- nn1 = [n1 | n2] (overwrites scratch region last) ----
  {
    int tot = N * 32;
    int g = (tot + 255) / 256; if (g > 4096) g = 4096;
    concat_k<<<g, 256, 0, stream>>>((const float4*)n1, (const float4*)n2, (float4*)out, N);
  }
}

// Round 2
// 1058.028 us; speedup vs baseline: 1.6472x; 1.6472x over previous
//
#include <hip/hip_runtime.h>

#define DD 128

typedef __attribute__((ext_vector_type(8))) short bh8;       // 8 bf16 (as i16 bits)
typedef __attribute__((ext_vector_type(8))) unsigned short us8;
typedef __attribute__((ext_vector_type(4))) float f4;
typedef unsigned int u32;

// ---------------- CSR build ----------------

__global__ __launch_bounds__(256) void init_counts_k(int* cn, int* ce, int N, int E, int NE) {
  int g = blockIdx.x * blockDim.x + threadIdx.x;
  if (g < NE) ce[g] = (g >= E) ? 1 : 0;
  if (g < N)  cn[g] = 1;
}

__global__ __launch_bounds__(256) void hist_k(const int* __restrict__ ni, const int* __restrict__ ei,
                                              int* cn, int* ce, int nnz) {
  int stride = gridDim.x * blockDim.x;
  for (int j = blockIdx.x * blockDim.x + threadIdx.x; j < nnz; j += stride) {
    atomicAdd(&cn[ni[j]], 1);
    atomicAdd(&ce[ei[j]], 1);
  }
}

// blockIdx 0 -> (cn,offs_n,N), 1 -> (ce,offs_e,NE)
__global__ __launch_bounds__(1024) void exscan2_k(const int* __restrict__ cn, int* offs_n, int N,
                                                  const int* __restrict__ ce, int* offs_e, int NE) {
  const int* cnt = blockIdx.x ? ce : cn;
  int* offs = blockIdx.x ? offs_e : offs_n;
  int n = blockIdx.x ? NE : N;
  __shared__ int sums[1024];
  __shared__ int carry;
  const int tid = threadIdx.x;
  if (tid == 0) carry = 0;
  __syncthreads();
  const int PER = 8;
  const int CH = 1024 * PER;
  for (int base = 0; base < n; base += CH) {
    int i0 = base + tid * PER;
    int v[PER]; int s = 0;
    #pragma unroll
    for (int j = 0; j < PER; ++j) { int i = i0 + j; int t = (i < n) ? cnt[i] : 0; v[j] = t; s += t; }
    sums[tid] = s;
    __syncthreads();
    for (int off = 1; off < 1024; off <<= 1) {
      int t = (tid >= off) ? sums[tid - off] : 0;
      __syncthreads();
      sums[tid] += t;
      __syncthreads();
    }
    int excl = sums[tid] - s + carry;
    #pragma unroll
    for (int j = 0; j < PER; ++j) { int i = i0 + j; if (i < n) offs[i] = excl; excl += v[j]; }
    __syncthreads();
    if (tid == 0) carry += sums[1023];
    __syncthreads();
  }
  if (tid == 0) offs[n] = carry;
}

__global__ __launch_bounds__(256) void fill_self_k(int* cur_n, int* cur_e, int* listN, int* listE,
                                                   const int* __restrict__ offs_n, const int* __restrict__ offs_e,
                                                   float* Dn_inv, float* De_inv,
                                                   int N, int E, int NE) {
  int g = blockIdx.x * blockDim.x + threadIdx.x;
  if (g < NE) {
    int b = offs_e[g], e = offs_e[g + 1];
    De_inv[g] = (e > b) ? 1.0f / (float)(e - b) : 0.0f;
    if (g < E) cur_e[g] = b;
    else { listE[b] = g - E; cur_e[g] = b + 1; }
  }
  if (g < N) {
    int b = offs_n[g], e = offs_n[g + 1];
    Dn_inv[g] = (e > b) ? 1.0f / (float)(e - b) : 0.0f;
    listN[b] = E + g; cur_n[g] = b + 1;
  }
}

__global__ __launch_bounds__(256) void fill_nnz_k(const int* __restrict__ ni, const int* __restrict__ ei,
                                                  int* cur_n, int* cur_e, int* listN, int* listE, int nnz) {
  int stride = gridDim.x * blockDim.x;
  for (int j = blockIdx.x * blockDim.x + threadIdx.x; j < nnz; j += stride) {
    int n = ni[j], e = ei[j];
    int pn = atomicAdd(&cur_n[n], 1); listN[pn] = e;
    int pe = atomicAdd(&cur_e[e], 1); listE[pe] = n;
  }
}

// ---------------- gather (ownership seg-sum, 1 wave/row, float2 lanes) ----------------
// MODE 0: dst = scale[row] * sum
// MODE 1: dst = prelu(scale[row]*sum + bias[c]); if dst2 && row<dst2_rows also store dst2
template<int MODE>
__global__ __launch_bounds__(256) void gather_k(const float* __restrict__ src,
                                                const int* __restrict__ offs, const int* __restrict__ list,
                                                const float* __restrict__ scale, const float* __restrict__ bias,
                                                const float* __restrict__ alphap, float* __restrict__ dst,
                                                float* __restrict__ dst2, int dst2_rows, int nrows) {
  const int wave = threadIdx.x >> 6, lane = threadIdx.x & 63;
  const int row = blockIdx.x * 4 + wave;
  if (row >= nrows) return;
  const int c2 = lane * 2;
  const int beg = offs[row], end = offs[row + 1];
  float2 a0 = {0.f, 0.f}, a1 = {0.f, 0.f}, a2 = {0.f, 0.f}, a3 = {0.f, 0.f};
  int i = beg;
  for (; i + 3 < end; i += 4) {
    int s0 = list[i], s1 = list[i + 1], s2 = list[i + 2], s3 = list[i + 3];
    float2 v0 = *(const float2*)&src[(size_t)s0 * DD + c2];
    float2 v1 = *(const float2*)&src[(size_t)s1 * DD + c2];
    float2 v2 = *(const float2*)&src[(size_t)s2 * DD + c2];
    float2 v3 = *(const float2*)&src[(size_t)s3 * DD + c2];
    a0.x += v0.x; a0.y += v0.y; a1.x += v1.x; a1.y += v1.y;
    a2.x += v2.x; a2.y += v2.y; a3.x += v3.x; a3.y += v3.y;
  }
  for (; i < end; ++i) {
    float2 v = *(const float2*)&src[(size_t)list[i] * DD + c2];
    a0.x += v.x; a0.y += v.y;
  }
  float sc = scale[row];
  float vx = sc * ((a0.x + a1.x) + (a2.x + a3.x));
  float vy = sc * ((a0.y + a1.y) + (a2.y + a3.y));
  if constexpr (MODE == 1) {
    float2 bt = *(const float2*)&bias[c2];
    float al = *alphap;
    vx += bt.x; vy += bt.y;
    vx = (vx >= 0.f) ? vx : al * vx;
    vy = (vy >= 0.f) ? vy : al * vy;
  }
  float2 o = {vx, vy};
  *(float2*)&dst[(size_t)row * DD + c2] = o;
  if constexpr (MODE == 1) {
    if (dst2 && row < dst2_rows) *(float2*)&dst2[(size_t)row * DD + c2] = o;
  }
}

// ---------------- weight prep: fp32 [k][n] -> LDS-image {hi[n][k], lo[n][k]} bf16, XOR-swizzled ----

struct WPtrs { const float* p[16]; };

__global__ __launch_bounds__(256) void prep_w_k(WPtrs wp, char* dst) {
  int m = blockIdx.x >> 3, s = blockIdx.x & 7;
  const float* W = wp.p[m];
  int t = threadIdx.x;
  int n = t & 127;
  int k0 = s * 16 + (t >> 7) * 8;
  us8 vhi, vlo;
  #pragma unroll
  for (int j = 0; j < 8; ++j) {
    float x = W[(size_t)(k0 + j) * DD + n];
    u32 ux = __builtin_bit_cast(u32, x);
    float hf = __builtin_bit_cast(float, ux & 0xFFFF0000u);
    float l = x - hf;
    vhi[j] = (unsigned short)(ux >> 16);
    vlo[j] = (unsigned short)(__builtin_bit_cast(u32, l) >> 16);
  }
  char* base = dst + (size_t)m * 65536;
  int byte = n * 256 + k0 * 2;
  byte ^= (n & 7) << 4;
  *(us8*)(base + byte) = vhi;
  *(us8*)(base + 32768 + byte) = vlo;
}

// ---------------- MFMA GEMM: (nrows x 128) @ (128 x 128), split-bf16 3-term ----------------

__device__ __forceinline__ void stage_w(const char* gsrc, char* lds, int tid) {
  int wave = tid >> 6, lane = tid & 63;
  #pragma unroll
  for (int i = 0; i < 16; ++i) {
    int off = (wave * 16 + i) * 1024;  // wave-uniform 1KB chunk
    __builtin_amdgcn_global_load_lds(
        (const __attribute__((address_space(1))) u32*)(gsrc + off + lane * 16),
        (__attribute__((address_space(3))) u32*)(lds + off), 16, 0, 0);
  }
}

__device__ __forceinline__ void mk_afrag(const float* rowp, int koff, bh8& hi, bh8& lo) {
  float4 v0 = *(const float4*)(rowp + koff);
  float4 v1 = *(const float4*)(rowp + koff + 4);
  float vs[8] = {v0.x, v0.y, v0.z, v0.w, v1.x, v1.y, v1.z, v1.w};
  #pragma unroll
  for (int j = 0; j < 8; ++j) {
    u32 u = __builtin_bit_cast(u32, vs[j]);
    float hf = __builtin_bit_cast(float, u & 0xFFFF0000u);
    float l = vs[j] - hf;
    hi[j] = (short)(u >> 16);
    lo[j] = (short)(__builtin_bit_cast(u32, l) >> 16);
  }
}

__device__ __forceinline__ void mfma_pass(const float* __restrict__ A, const char* Wl,
                                          int rbase, int nrows, int lane, f4 acc[8]) {
  int r = rbase + (lane & 15);
  if (r >= nrows) r = nrows - 1;
  const float* rowp = A + (size_t)r * DD;
  const int koff0 = (lane >> 4) * 8;
  #pragma unroll
  for (int ks = 0; ks < 4; ++ks) {
    bh8 ahi, alo;
    mk_afrag(rowp, ks * 32 + koff0, ahi, alo);
    const int k2 = (ks * 32 + koff0) * 2;
    #pragma unroll
    for (int cb = 0; cb < 8; ++cb) {
      int n = cb * 16 + (lane & 15);
      int byte = (n * 256 + k2) ^ ((n & 7) << 4);
      bh8 bhiF = *(const bh8*)(Wl + byte);
      bh8 bloF = *(const bh8*)(Wl + 32768 + byte);
      acc[cb] = __builtin_amdgcn_mfma_f32_16x16x32_bf16(ahi, bhiF, acc[cb], 0, 0, 0);
      acc[cb] = __builtin_amdgcn_mfma_f32_16x16x32_bf16(ahi, bloF, acc[cb], 0, 0, 0);
      acc[cb] = __builtin_amdgcn_mfma_f32_16x16x32_bf16(alo, bhiF, acc[cb], 0, 0, 0);
    }
  }
}

template<int MODE>
__device__ __forceinline__ void epilogue(f4 acc[8], const float* bias, const float* alphap,
                                         float* out, int rbase, int nrows, int lane) {
  float al = 0.f;
  if constexpr (MODE == 1) al = *alphap;
  const int cidx = lane & 15;
  int rq = rbase + (lane >> 4) * 4;
  float b8[8];
  if constexpr (MODE == 1) {
    #pragma unroll
    for (int cb = 0; cb < 8; ++cb) b8[cb] = bias[cb * 16 + cidx];
  }
  #pragma unroll
  for (int q = 0; q < 4; ++q) {
    int row = rq + q;
    if (row < nrows) {
      float* op = out + (size_t)row * DD + cidx;
      #pragma unroll
      for (int cb = 0; cb < 8; ++cb) {
        float v = acc[cb][q];
        if constexpr (MODE == 1) { v += b8[cb]; v = (v >= 0.f) ? v : al * v; }
        op[cb * 16] = v;
      }
    }
  }
}

// MODE 0: out = A@W    MODE 1: out = prelu(A@W + bias)
template<int MODE>
__global__ __launch_bounds__(256, 2) void gemm_mfma_k(const float* __restrict__ A, const char* __restrict__ Wprep,
                                                      const float* __restrict__ bias, const float* __restrict__ alphap,
                                                      float* __restrict__ out, int nrows) {
  __shared__ char Wl[65536];
  stage_w(Wprep, Wl, threadIdx.x);
  __syncthreads();
  const int wave = threadIdx.x >> 6, lane = threadIdx.x & 63;
  const int rbase = blockIdx.x * 64 + wave * 16;
  f4 acc[8];
  #pragma unroll
  for (int cb = 0; cb < 8; ++cb) acc[cb] = {0.f, 0.f, 0.f, 0.f};
  mfma_pass(A, Wl, rbase, nrows, lane, acc);
  epilogue<MODE>(acc, bias, alphap, out, rbase, nrows, lane);
}

// out = prelu(A1@W1 + A2@W2 + bias)
__global__ __launch_bounds__(256, 2) void gemm_mfma_dual_k(const float* __restrict__ A1, const char* __restrict__ W1,
                                                           const float* __restrict__ A2, const char* __restrict__ W2,
                                                           const float* __restrict__ bias, const float* __restrict__ alphap,
                                                           float* __restrict__ out, int nrows) {
  __shared__ char Wl[65536];
  stage_w(W1, Wl, threadIdx.x);
  __syncthreads();
  const int wave = threadIdx.x >> 6, lane = threadIdx.x & 63;
  const int rbase = blockIdx.x * 64 + wave * 16;
  f4 acc[8];
  #pragma unroll
  for (int cb = 0; cb < 8; ++cb) acc[cb] = {0.f, 0.f, 0.f, 0.f};
  mfma_pass(A1, Wl, rbase, nrows, lane, acc);
  __syncthreads();
  stage_w(W2, Wl, threadIdx.x);
  __syncthreads();
  mfma_pass(A2, Wl, rbase, nrows, lane, acc);
  epilogue<1>(acc, bias, alphap, out, rbase, nrows, lane);
}

// ---------------- copies ----------------

__global__ __launch_bounds__(256) void copy4_k(const float4* __restrict__ src, float4* __restrict__ dst, int n4) {
  int stride = gridDim.x * blockDim.x;
  for (int i = blockIdx.x * blockDim.x + threadIdx.x; i < n4; i += stride) dst[i] = src[i];
}

__global__ __launch_bounds__(256) void concat_k(const float4* __restrict__ n1, const float4* __restrict__ n2,
                                                float4* __restrict__ nn1, int N) {
  int stride = gridDim.x * blockDim.x;
  int tot = N * 32;
  for (int g = blockIdx.x * blockDim.x + threadIdx.x; g < tot; g += stride) {
    int r = g >> 5, q = g & 31;
    nn1[(size_t)r * 64 + q] = n1[g];
    nn1[(size_t)r * 64 + 32 + q] = n2[g];
  }
}

// ---------------- host ----------------

extern "C" void kernel_launch(void* const* d_in, const int* in_sizes, int n_in,
                              void* d_out, int out_size, void* d_ws, size_t ws_size,
                              hipStream_t stream) {
  const float* x        = (const float*)d_in[0];
  const float* xx       = (const float*)d_in[1];
  const int*   node_idx = (const int*)d_in[2];
  const int*   edge_idx = (const int*)d_in[3];
  const float* alphap   = (const float*)d_in[6];
  const float* e1_Wn2e  = (const float*)d_in[7];
  const float* e1_bn2e  = (const float*)d_in[8];
  const float* e1_We2n  = (const float*)d_in[9];
  const float* e1_be2n  = (const float*)d_in[10];
  const float* e2_Wn2e  = (const float*)d_in[11];
  const float* e2_bn2e  = (const float*)d_in[12];
  const float* e2_We2n  = (const float*)d_in[13];
  const float* e2_be2n  = (const float*)d_in[14];
  const float* d1_We    = (const float*)d_in[15];
  const float* d1_Wx    = (const float*)d_in[16];
  const float* d1_b     = (const float*)d_in[17];
  const float* d2_We    = (const float*)d_in[18];
  const float* d2_Wx    = (const float*)d_in[19];
  const float* d2_b     = (const float*)d_in[20];

  const int N   = in_sizes[0] / DD;
  const int NNZ = in_sizes[2];
  const int E   = (out_size - 1024 * N) / 256;
  const int NE  = E + N;
  const long long M = (long long)NNZ + N;

  // ---- workspace carve ----
  char* w0 = (char*)d_ws;
  size_t off = 0;
  auto carve = [&](size_t bytes) -> void* {
    void* p = (void*)(w0 + off);
    off += (bytes + 255) & ~(size_t)255;
    return p;
  };
  int* cn      = (int*)carve((size_t)N * 4);
  int* ce      = (int*)carve((size_t)NE * 4);
  int* offs_n  = (int*)carve((size_t)(N + 1) * 4);
  int* offs_e  = (int*)carve((size_t)(NE + 1) * 4);
  int* cur_n   = (int*)carve((size_t)N * 4);
  int* cur_e   = (int*)carve((size_t)NE * 4);
  int* listN   = (int*)carve((size_t)M * 4);
  int* listE   = (int*)carve((size_t)M * 4);
  float* Dn_inv = (float*)carve((size_t)N * 4);
  float* De_inv = (float*)carve((size_t)NE * 4);
  float* e_full = (float*)carve((size_t)NE * DD * 4);
  char* Wprep  = (char*)carve((size_t)16 * 65536);
  // optional aggregates in workspace (direct decoder writes)
  bool ws_aggs = (off + 2 * ((size_t)N * DD * 4 + 256)) <= ws_size;
  float* agg1_ws = nullptr, *agg2_ws = nullptr;
  if (ws_aggs) {
    agg1_ws = (float*)carve((size_t)N * DD * 4);
    agg2_ws = (float*)carve((size_t)N * DD * 4);
  }

  // ---- d_out slot map ----
  float* out  = (float*)d_out;
  float* scrA = out;                       // nn1 region (finalized last)
  float* scrB = out + (size_t)N * DD;
  float* n1   = out + (size_t)N * 256;
  float* e1o  = n1 + (size_t)N * DD;
  float* n2   = e1o + (size_t)E * DD;
  float* e2o  = n2 + (size_t)N * DD;
  float* x11  = e2o + (size_t)E * DD;
  float* x21  = x11 + (size_t)N * DD;
  float* x12  = x21 + (size_t)N * DD;
  float* x22  = x12 + (size_t)N * DD;
  float* agg1 = ws_aggs ? agg1_ws : x22;
  float* agg2 = ws_aggs ? agg2_ws : x21;

  // ---- weight prep table ----
  WPtrs wp;
  wp.p[0] = e1_Wn2e;              wp.p[1] = e1_Wn2e + DD * DD;
  wp.p[2] = e1_We2n;              wp.p[3] = e1_We2n + DD * DD;
  wp.p[4] = e2_Wn2e;              wp.p[5] = e2_Wn2e + DD * DD;
  wp.p[6] = e2_We2n;              wp.p[7] = e2_We2n + DD * DD;
  wp.p[8] = d1_We;                wp.p[9] = d1_We + DD * DD;
  wp.p[10] = d1_Wx;               wp.p[11] = d1_Wx + DD * DD;
  wp.p[12] = d2_We;               wp.p[13] = d2_We + DD * DD;
  wp.p[14] = d2_Wx;               wp.p[15] = d2_Wx + DD * DD;
  auto WP = [&](int i) -> const char* { return Wprep + (size_t)i * 65536; };

  const int thr = 256;
  const int gNE = (NE + thr - 1) / thr;
  int gNNZ = (NNZ + thr - 1) / thr; if (gNNZ > 2048) gNNZ = 2048;
  const int gGemm = (N + 63) / 64;
  const int gGatE = (NE + 3) / 4;
  const int gGatN = (N + 3) / 4;

  // ---- weight prep + CSR build ----
  prep_w_k<<<128, 256, 0, stream>>>(wp, Wprep);
  init_counts_k<<<gNE, thr, 0, stream>>>(cn, ce, N, E, NE);
  hist_k<<<gNNZ, thr, 0, stream>>>(node_idx, edge_idx, cn, ce, NNZ);
  exscan2_k<<<2, 1024, 0, stream>>>(cn, offs_n, N, ce, offs_e, NE);
  fill_self_k<<<gNE, thr, 0, stream>>>(cur_n, cur_e, listN, listE, offs_n, offs_e, Dn_inv, De_inv, N, E, NE);
  fill_nnz_k<<<gNNZ, thr, 0, stream>>>(node_idx, edge_idx, cur_n, cur_e, listN, listE, NNZ);

  // ---- encoder ----
  auto encoder = [&](const float* X0, int wn2e0, const float* bn2e, int we2n0, const float* be2n,
                     float* nOut, float* aggOut, float* eOut) {
    // layer 0
    gemm_mfma_k<0><<<gGemm, 256, 0, stream>>>(X0, WP(wn2e0), nullptr, nullptr, scrA, N);
    gather_k<1><<<gGatE, 256, 0, stream>>>(scrA, offs_e, listE, De_inv, bn2e, alphap, e_full, nullptr, 0, NE);
    gather_k<0><<<gGatN, 256, 0, stream>>>(e_full, offs_n, listN, Dn_inv, nullptr, nullptr, scrA, nullptr, 0, N);
    gemm_mfma_k<1><<<gGemm, 256, 0, stream>>>(scrA, WP(we2n0), be2n, alphap, scrB, N);
    // layer 1
    gemm_mfma_k<0><<<gGemm, 256, 0, stream>>>(scrB, WP(wn2e0 + 1), nullptr, nullptr, scrA, N);
    gather_k<1><<<gGatE, 256, 0, stream>>>(scrA, offs_e, listE, De_inv, bn2e + DD, alphap, e_full, eOut, E, NE);
    gather_k<0><<<gGatN, 256, 0, stream>>>(e_full, offs_n, listN, Dn_inv, nullptr, nullptr, aggOut, nullptr, 0, N);
    gemm_mfma_k<1><<<gGemm, 256, 0, stream>>>(aggOut, WP(we2n0 + 1), be2n + DD, alphap, nOut, N);
  };

  encoder(x,  0, e1_bn2e, 2, e1_be2n, n1, agg1, e1o);
  encoder(xx, 4, e2_bn2e, 6, e2_be2n, n2, agg2, e2o);

  // ---- decoders ----
  auto decoder = [&](const float* x0, const float* agg, int we0, int wx0,
                     const float* b, float* outSlot, bool direct) {
    float* tgt = direct ? outSlot : scrA;
    gemm_mfma_dual_k<<<gGemm, 256, 0, stream>>>(x0, WP(wx0), agg, WP(we0), b, alphap, scrB, N);
    gemm_mfma_dual_k<<<gGemm, 256, 0, stream>>>(scrB, WP(wx0 + 1), agg, WP(we0 + 1), b + DD, alphap, tgt, N);
    if (!direct) {
      int n4 = N * 32;
      int g = (n4 + 255) / 256; if (g > 2048) g = 2048;
      copy4_k<<<g, 256, 0, stream>>>((const float4*)scrA, (float4*)outSlot, n4);
    }
  };

  // order: x11, x12 first (direct always); x22/x21 last (they overwrite agg slots in fallback)
  decoder(n1, agg1, 8, 10, d1_b, x11, true);
  decoder(n2, agg2, 8, 10, d1_b, x12, true);
  decoder(n1, agg1, 12, 14, d2_b, x22, ws_aggs);
  decoder(n2, agg2, 12, 14, d2_b, x21, ws_aggs);

  // ---- nn1 = [n1 | n2] ----
  {
    int tot = N * 32;
    int g = (tot + 255) / 256; if (g > 4096) g = 4096;
    concat_k<<<g, 256, 0, stream>>>((const float4*)n1, (const float4*)n2, (float4*)out, N);
  }
}